// Round 2
// baseline (148.218 us; speedup 1.0000x reference)
//
#include <hip/hip_runtime.h>

// PointNetKnnInterpolator on MI355X (gfx950).
// h = [x[x_idx], pos_x[x_idx]-pos_y[y_idx]]  (400000 x 67)
// net = relu(h)@W0a+b0a ; dx = relu(net)@W1a+b1a ; h2 = h@Wsa + dx
// net2 = relu(h2)@W0b+b0b ; h3 = h2 + relu(net2)@W1b+b1b
// out[y] = max over 8 consecutive rows of h3.
//
// One wave = one 16-row tile (2 y-points). f16 MFMA 16x16x32, fp32 accum.
// Weights pre-expanded per block into LDS in B-fragment order (48 frags):
//   B frag read = ds_read_b128 at (fragbase + lane*16)  (conflict floor).
// A side gathered directly from global into registers (lane m = lane&15).
// C->A layout transpose via small per-wave LDS buffer.

typedef _Float16 f16x8 __attribute__((ext_vector_type(8)));
typedef float    f32x4 __attribute__((ext_vector_type(4)));

constexpr int NROWS   = 50000 * 8;   // NY * K
constexpr int NTILES  = NROWS / 16;  // 25000
constexpr int NFRAG   = 48;          // 12 (W0a) + 8 (W1a) + 12 (Wsa) + 8 (W0b) + 8 (W1b)
constexpr int TSTRIDE = 72;          // halves per row of transition buffer (144 B, 16B-aligned rows)

__global__ __launch_bounds__(256, 2)
void pointnet_fused(const float* __restrict__ x,
                    const float* __restrict__ pos_x,
                    const float* __restrict__ pos_y,
                    const int*   __restrict__ x_idx,
                    const float* __restrict__ W0a, const float* __restrict__ b0a,
                    const float* __restrict__ W1a, const float* __restrict__ b1a,
                    const float* __restrict__ Wsa,
                    const float* __restrict__ W0b, const float* __restrict__ b0b,
                    const float* __restrict__ W1b, const float* __restrict__ b1b,
                    float* __restrict__ out)
{
    __shared__ __align__(16) _Float16 bfrag[NFRAG * 64 * 8];      // 48 KiB
    __shared__ __align__(16) _Float16 trans[4][16 * TSTRIDE];     // 9 KiB (per-wave buffers)

    const int tid = threadIdx.x;

    // ---- expand weights into B-fragment order (once per block) ----
    // frag ids: 0..11 W0a (s=0..2), 12..19 W1a (s=0..1), 20..31 Wsa,
    //           32..39 W0b, 40..47 W1b.  id-in-group = s*4 + t.
    for (int p = tid; p < NFRAG * 64; p += 256) {
        const int f = p >> 6;
        const int l = p & 63;
        const float* W; int krows, fl;
        if (f < 12)      { W = W0a; krows = 67; fl = f; }
        else if (f < 20) { W = W1a; krows = 64; fl = f - 12; }
        else if (f < 32) { W = Wsa; krows = 67; fl = f - 20; }
        else if (f < 40) { W = W0b; krows = 64; fl = f - 32; }
        else             { W = W1b; krows = 64; fl = f - 40; }
        const int s = fl >> 2, t = fl & 3;
        const int n = t * 16 + (l & 15);
        const int kbase = s * 32 + (l >> 4) * 8;
        f16x8 v;
#pragma unroll
        for (int j = 0; j < 8; ++j) {
            const int k = kbase + j;
            v[j] = (_Float16)((k < krows) ? W[k * 64 + n] : 0.0f);
        }
        *(f16x8*)&bfrag[p * 8] = v;
    }
    __syncthreads();

    const int lane = tid & 63;
    const int wv   = tid >> 6;
    const int n0   = lane & 15;   // C col / A row m
    const int q    = lane >> 4;   // quad

    // biases are constant per lane across tiles — preload
    float bias0a[4], bias1a[4], bias0b[4], bias1b[4];
#pragma unroll
    for (int t = 0; t < 4; ++t) {
        bias0a[t] = b0a[t * 16 + n0];
        bias1a[t] = b1a[t * 16 + n0];
        bias0b[t] = b0b[t * 16 + n0];
        bias1b[t] = b1b[t * 16 + n0];
    }

    _Float16* tbuf = trans[wv];
    const int gwave  = blockIdx.x * 4 + wv;
    const int nwaves = gridDim.x * 4;

    for (int tile = gwave; tile < NTILES; tile += nwaves) {
        // ---- gather A fragments: h (raw) and relu(h), K padded 67->96 ----
        const int row = tile * 16 + n0;       // this lane's A row (m = n0)
        const int xi  = x_idx[row];
        const float* xp = x + (long)xi * 64;
        f16x8 hn[3], hr[3];
#pragma unroll
        for (int s = 0; s < 2; ++s) {
            const float4* src = (const float4*)(xp + s * 32 + q * 8);
            float4 v0 = src[0], v1 = src[1];
            float vals[8] = {v0.x, v0.y, v0.z, v0.w, v1.x, v1.y, v1.z, v1.w};
#pragma unroll
            for (int j = 0; j < 8; ++j) {
                const float fv = vals[j];
                hn[s][j] = (_Float16)fv;
                hr[s][j] = (_Float16)(fv > 0.0f ? fv : 0.0f);
            }
        }
        {
            f16x8 z = {};
            hn[2] = z; hr[2] = z;
            if (q == 0) {                      // k = 64..66 -> diff dims
                const int yi = row >> 3;
#pragma unroll
                for (int j = 0; j < 3; ++j) {
                    const float d = pos_x[xi * 3 + j] - pos_y[yi * 3 + j];
                    hn[2][j] = (_Float16)d;
                    hr[2][j] = (_Float16)(d > 0.0f ? d : 0.0f);
                }
            }
        }

        // ---- mm1: net = relu(h) @ W0a + b0a ----
        f32x4 acc[4];
#pragma unroll
        for (int t = 0; t < 4; ++t)
            acc[t] = (f32x4){bias0a[t], bias0a[t], bias0a[t], bias0a[t]};
#pragma unroll
        for (int s = 0; s < 3; ++s)
#pragma unroll
            for (int t = 0; t < 4; ++t) {
                f16x8 b = *(const f16x8*)&bfrag[((s * 4 + t) * 64 + lane) * 8];
                acc[t] = __builtin_amdgcn_mfma_f32_16x16x32_f16(hr[s], b, acc[t], 0, 0, 0);
            }

        // relu(net) -> tbuf (C layout), reload as A frags
        __threadfence_block();
#pragma unroll
        for (int t = 0; t < 4; ++t)
#pragma unroll
            for (int r = 0; r < 4; ++r) {
                float v = acc[t][r];
                tbuf[(q * 4 + r) * TSTRIDE + t * 16 + n0] = (_Float16)(v > 0.0f ? v : 0.0f);
            }
        __threadfence_block();
        f16x8 a2[2];
#pragma unroll
        for (int s = 0; s < 2; ++s)
            a2[s] = *(const f16x8*)&tbuf[n0 * TSTRIDE + s * 32 + q * 8];

        // ---- mm2+mm3: h2 = relu(net)@W1a + b1a + h@Wsa ----
        f32x4 acc2[4];
#pragma unroll
        for (int t = 0; t < 4; ++t)
            acc2[t] = (f32x4){bias1a[t], bias1a[t], bias1a[t], bias1a[t]};
#pragma unroll
        for (int s = 0; s < 2; ++s)
#pragma unroll
            for (int t = 0; t < 4; ++t) {
                f16x8 b = *(const f16x8*)&bfrag[((12 + s * 4 + t) * 64 + lane) * 8];
                acc2[t] = __builtin_amdgcn_mfma_f32_16x16x32_f16(a2[s], b, acc2[t], 0, 0, 0);
            }
#pragma unroll
        for (int s = 0; s < 3; ++s)
#pragma unroll
            for (int t = 0; t < 4; ++t) {
                f16x8 b = *(const f16x8*)&bfrag[((20 + s * 4 + t) * 64 + lane) * 8];
                acc2[t] = __builtin_amdgcn_mfma_f32_16x16x32_f16(hn[s], b, acc2[t], 0, 0, 0);
            }

        // relu(h2) -> tbuf -> A frags   (acc2 keeps h2 for the residual)
        __threadfence_block();
#pragma unroll
        for (int t = 0; t < 4; ++t)
#pragma unroll
            for (int r = 0; r < 4; ++r) {
                float v = acc2[t][r];
                tbuf[(q * 4 + r) * TSTRIDE + t * 16 + n0] = (_Float16)(v > 0.0f ? v : 0.0f);
            }
        __threadfence_block();
        f16x8 a4[2];
#pragma unroll
        for (int s = 0; s < 2; ++s)
            a4[s] = *(const f16x8*)&tbuf[n0 * TSTRIDE + s * 32 + q * 8];

        // ---- mm4: net2 = relu(h2)@W0b + b0b ----
        f32x4 acc3[4];
#pragma unroll
        for (int t = 0; t < 4; ++t)
            acc3[t] = (f32x4){bias0b[t], bias0b[t], bias0b[t], bias0b[t]};
#pragma unroll
        for (int s = 0; s < 2; ++s)
#pragma unroll
            for (int t = 0; t < 4; ++t) {
                f16x8 b = *(const f16x8*)&bfrag[((32 + s * 4 + t) * 64 + lane) * 8];
                acc3[t] = __builtin_amdgcn_mfma_f32_16x16x32_f16(a4[s], b, acc3[t], 0, 0, 0);
            }

        // relu(net2) -> tbuf -> A frags
        __threadfence_block();
#pragma unroll
        for (int t = 0; t < 4; ++t)
#pragma unroll
            for (int r = 0; r < 4; ++r) {
                float v = acc3[t][r];
                tbuf[(q * 4 + r) * TSTRIDE + t * 16 + n0] = (_Float16)(v > 0.0f ? v : 0.0f);
            }
        __threadfence_block();
        f16x8 a5[2];
#pragma unroll
        for (int s = 0; s < 2; ++s)
            a5[s] = *(const f16x8*)&tbuf[n0 * TSTRIDE + s * 32 + q * 8];

        // ---- mm5: h3 = h2 + relu(net2)@W1b + b1b ----
        f32x4 acc4[4];
#pragma unroll
        for (int t = 0; t < 4; ++t) {
            acc4[t] = acc2[t];
            acc4[t][0] += bias1b[t]; acc4[t][1] += bias1b[t];
            acc4[t][2] += bias1b[t]; acc4[t][3] += bias1b[t];
        }
#pragma unroll
        for (int s = 0; s < 2; ++s)
#pragma unroll
            for (int t = 0; t < 4; ++t) {
                f16x8 b = *(const f16x8*)&bfrag[((40 + s * 4 + t) * 64 + lane) * 8];
                acc4[t] = __builtin_amdgcn_mfma_f32_16x16x32_f16(a5[s], b, acc4[t], 0, 0, 0);
            }

        // ---- segment max over 8 rows (q0|q1 -> y0, q2|q3 -> y1) & store ----
#pragma unroll
        for (int t = 0; t < 4; ++t) {
            float pm = fmaxf(fmaxf(acc4[t][0], acc4[t][1]),
                             fmaxf(acc4[t][2], acc4[t][3]));
            pm = fmaxf(pm, __shfl_xor(pm, 16, 64));
            if ((q & 1) == 0) {
                const int y = tile * 2 + (q >> 1);
                out[(long)y * 64 + t * 16 + n0] = pm;
            }
        }
    }
}

extern "C" void kernel_launch(void* const* d_in, const int* in_sizes, int n_in,
                              void* d_out, int out_size, void* d_ws, size_t ws_size,
                              hipStream_t stream) {
    (void)in_sizes; (void)n_in; (void)d_ws; (void)ws_size; (void)out_size;
    pointnet_fused<<<512, 256, 0, stream>>>(
        (const float*)d_in[0],   // x
        (const float*)d_in[1],   // pos_x
        (const float*)d_in[2],   // pos_y
        (const int*)  d_in[3],   // x_idx
        (const float*)d_in[5],  (const float*)d_in[6],   // W0a, b0a
        (const float*)d_in[7],  (const float*)d_in[8],   // W1a, b1a
        (const float*)d_in[9],                            // Wsa
        (const float*)d_in[10], (const float*)d_in[11],  // W0b, b0b
        (const float*)d_in[12], (const float*)d_in[13],  // W1b, b1b
        (float*)d_out);
}

// Round 3
// 126.585 us; speedup vs baseline: 1.1709x; 1.1709x over previous
//
#include <hip/hip_runtime.h>

// PointNetKnnInterpolator on MI355X (gfx950).
// h = [x[x_idx], pos_x[x_idx]-pos_y[y_idx]]  (400000 x 67)
// net = relu(h)@W0a+b0a ; dx = relu(net)@W1a+b1a ; h2 = h@Wsa + dx
// net2 = relu(h2)@W0b+b0b ; h3 = h2 + relu(net2)@W1b+b1b
// out[y] = max over 8 consecutive rows of h3.
//
// One wave = one 16-row tile (2 y-points). f16 MFMA 16x16x32, fp32 accum.
// R3: block=512 (8 waves) sharing ONE 48 KB bfrag copy -> LDS 66 KB,
//     2 blocks/CU = 16 waves/CU (4/SIMD) vs R2's 8 waves/CU. The R2 profile
//     showed all pipes idle at Occupancy 21% -> latency-bound; this doubles
//     latency hiding without touching the algorithm.

typedef _Float16 f16x8 __attribute__((ext_vector_type(8)));
typedef float    f32x4 __attribute__((ext_vector_type(4)));

constexpr int NROWS   = 50000 * 8;   // NY * K
constexpr int NTILES  = NROWS / 16;  // 25000
constexpr int NFRAG   = 48;          // 12 (W0a) + 8 (W1a) + 12 (Wsa) + 8 (W0b) + 8 (W1b)
constexpr int TSTRIDE = 72;          // halves per row of transition buffer (144 B, 16B-aligned rows)
constexpr int BW      = 8;           // waves per block (block = 512 threads)

__global__ __launch_bounds__(512, 4)
void pointnet_fused(const float* __restrict__ x,
                    const float* __restrict__ pos_x,
                    const float* __restrict__ pos_y,
                    const int*   __restrict__ x_idx,
                    const float* __restrict__ W0a, const float* __restrict__ b0a,
                    const float* __restrict__ W1a, const float* __restrict__ b1a,
                    const float* __restrict__ Wsa,
                    const float* __restrict__ W0b, const float* __restrict__ b0b,
                    const float* __restrict__ W1b, const float* __restrict__ b1b,
                    float* __restrict__ out)
{
    __shared__ __align__(16) _Float16 bfrag[NFRAG * 64 * 8];       // 48 KiB (shared by all 8 waves)
    __shared__ __align__(16) _Float16 trans[BW][16 * TSTRIDE];     // 18 KiB (per-wave buffers)

    const int tid = threadIdx.x;

    // ---- expand weights into B-fragment order (once per block) ----
    // frag ids: 0..11 W0a (s=0..2), 12..19 W1a (s=0..1), 20..31 Wsa,
    //           32..39 W0b, 40..47 W1b.  id-in-group = s*4 + t.
    for (int p = tid; p < NFRAG * 64; p += 512) {
        const int f = p >> 6;
        const int l = p & 63;
        const float* W; int krows, fl;
        if (f < 12)      { W = W0a; krows = 67; fl = f; }
        else if (f < 20) { W = W1a; krows = 64; fl = f - 12; }
        else if (f < 32) { W = Wsa; krows = 67; fl = f - 20; }
        else if (f < 40) { W = W0b; krows = 64; fl = f - 32; }
        else             { W = W1b; krows = 64; fl = f - 40; }
        const int s = fl >> 2, t = fl & 3;
        const int n = t * 16 + (l & 15);
        const int kbase = s * 32 + (l >> 4) * 8;
        f16x8 v;
#pragma unroll
        for (int j = 0; j < 8; ++j) {
            const int k = kbase + j;
            v[j] = (_Float16)((k < krows) ? W[k * 64 + n] : 0.0f);
        }
        *(f16x8*)&bfrag[p * 8] = v;
    }
    __syncthreads();

    const int lane = tid & 63;
    const int wv   = tid >> 6;
    const int n0   = lane & 15;   // C col / A row m
    const int q    = lane >> 4;   // quad

    // biases are constant per lane across tiles — preload
    float bias0a[4], bias1a[4], bias0b[4], bias1b[4];
#pragma unroll
    for (int t = 0; t < 4; ++t) {
        bias0a[t] = b0a[t * 16 + n0];
        bias1a[t] = b1a[t * 16 + n0];
        bias0b[t] = b0b[t * 16 + n0];
        bias1b[t] = b1b[t * 16 + n0];
    }

    _Float16* tbuf = trans[wv];
    const int gwave  = blockIdx.x * BW + wv;
    const int nwaves = gridDim.x * BW;

    for (int tile = gwave; tile < NTILES; tile += nwaves) {
        // ---- gather A fragments: h (raw) and relu(h), K padded 67->96 ----
        const int row = tile * 16 + n0;       // this lane's A row (m = n0)
        const int xi  = x_idx[row];
        const float* xp = x + (long)xi * 64;
        f16x8 hn[3], hr[3];
#pragma unroll
        for (int s = 0; s < 2; ++s) {
            const float4* src = (const float4*)(xp + s * 32 + q * 8);
            float4 v0 = src[0], v1 = src[1];
            float vals[8] = {v0.x, v0.y, v0.z, v0.w, v1.x, v1.y, v1.z, v1.w};
#pragma unroll
            for (int j = 0; j < 8; ++j) {
                const float fv = vals[j];
                hn[s][j] = (_Float16)fv;
                hr[s][j] = (_Float16)(fv > 0.0f ? fv : 0.0f);
            }
        }
        {
            f16x8 z = {};
            hn[2] = z; hr[2] = z;
            if (q == 0) {                      // k = 64..66 -> diff dims
                const int yi = row >> 3;
#pragma unroll
                for (int j = 0; j < 3; ++j) {
                    const float d = pos_x[xi * 3 + j] - pos_y[yi * 3 + j];
                    hn[2][j] = (_Float16)d;
                    hr[2][j] = (_Float16)(d > 0.0f ? d : 0.0f);
                }
            }
        }

        // ---- mm1: net = relu(h) @ W0a + b0a ----
        f32x4 acc[4];
#pragma unroll
        for (int t = 0; t < 4; ++t)
            acc[t] = (f32x4){bias0a[t], bias0a[t], bias0a[t], bias0a[t]};
#pragma unroll
        for (int s = 0; s < 3; ++s)
#pragma unroll
            for (int t = 0; t < 4; ++t) {
                f16x8 b = *(const f16x8*)&bfrag[((s * 4 + t) * 64 + lane) * 8];
                acc[t] = __builtin_amdgcn_mfma_f32_16x16x32_f16(hr[s], b, acc[t], 0, 0, 0);
            }

        // relu(net) -> tbuf (C layout), reload as A frags
        __threadfence_block();
#pragma unroll
        for (int t = 0; t < 4; ++t)
#pragma unroll
            for (int r = 0; r < 4; ++r) {
                float v = acc[t][r];
                tbuf[(q * 4 + r) * TSTRIDE + t * 16 + n0] = (_Float16)(v > 0.0f ? v : 0.0f);
            }
        __threadfence_block();
        f16x8 a2[2];
#pragma unroll
        for (int s = 0; s < 2; ++s)
            a2[s] = *(const f16x8*)&tbuf[n0 * TSTRIDE + s * 32 + q * 8];

        // ---- mm2+mm3: h2 = relu(net)@W1a + b1a + h@Wsa ----
        f32x4 acc2[4];
#pragma unroll
        for (int t = 0; t < 4; ++t)
            acc2[t] = (f32x4){bias1a[t], bias1a[t], bias1a[t], bias1a[t]};
#pragma unroll
        for (int s = 0; s < 2; ++s)
#pragma unroll
            for (int t = 0; t < 4; ++t) {
                f16x8 b = *(const f16x8*)&bfrag[((12 + s * 4 + t) * 64 + lane) * 8];
                acc2[t] = __builtin_amdgcn_mfma_f32_16x16x32_f16(a2[s], b, acc2[t], 0, 0, 0);
            }
#pragma unroll
        for (int s = 0; s < 3; ++s)
#pragma unroll
            for (int t = 0; t < 4; ++t) {
                f16x8 b = *(const f16x8*)&bfrag[((20 + s * 4 + t) * 64 + lane) * 8];
                acc2[t] = __builtin_amdgcn_mfma_f32_16x16x32_f16(hn[s], b, acc2[t], 0, 0, 0);
            }

        // relu(h2) -> tbuf -> A frags   (acc2 keeps h2 for the residual)
        __threadfence_block();
#pragma unroll
        for (int t = 0; t < 4; ++t)
#pragma unroll
            for (int r = 0; r < 4; ++r) {
                float v = acc2[t][r];
                tbuf[(q * 4 + r) * TSTRIDE + t * 16 + n0] = (_Float16)(v > 0.0f ? v : 0.0f);
            }
        __threadfence_block();
        f16x8 a4[2];
#pragma unroll
        for (int s = 0; s < 2; ++s)
            a4[s] = *(const f16x8*)&tbuf[n0 * TSTRIDE + s * 32 + q * 8];

        // ---- mm4: net2 = relu(h2)@W0b + b0b ----
        f32x4 acc3[4];
#pragma unroll
        for (int t = 0; t < 4; ++t)
            acc3[t] = (f32x4){bias0b[t], bias0b[t], bias0b[t], bias0b[t]};
#pragma unroll
        for (int s = 0; s < 2; ++s)
#pragma unroll
            for (int t = 0; t < 4; ++t) {
                f16x8 b = *(const f16x8*)&bfrag[((32 + s * 4 + t) * 64 + lane) * 8];
                acc3[t] = __builtin_amdgcn_mfma_f32_16x16x32_f16(a4[s], b, acc3[t], 0, 0, 0);
            }

        // relu(net2) -> tbuf -> A frags
        __threadfence_block();
#pragma unroll
        for (int t = 0; t < 4; ++t)
#pragma unroll
            for (int r = 0; r < 4; ++r) {
                float v = acc3[t][r];
                tbuf[(q * 4 + r) * TSTRIDE + t * 16 + n0] = (_Float16)(v > 0.0f ? v : 0.0f);
            }
        __threadfence_block();
        f16x8 a5[2];
#pragma unroll
        for (int s = 0; s < 2; ++s)
            a5[s] = *(const f16x8*)&tbuf[n0 * TSTRIDE + s * 32 + q * 8];

        // ---- mm5: h3 = h2 + relu(net2)@W1b + b1b ----
        f32x4 acc4[4];
#pragma unroll
        for (int t = 0; t < 4; ++t) {
            acc4[t] = acc2[t];
            acc4[t][0] += bias1b[t]; acc4[t][1] += bias1b[t];
            acc4[t][2] += bias1b[t]; acc4[t][3] += bias1b[t];
        }
#pragma unroll
        for (int s = 0; s < 2; ++s)
#pragma unroll
            for (int t = 0; t < 4; ++t) {
                f16x8 b = *(const f16x8*)&bfrag[((40 + s * 4 + t) * 64 + lane) * 8];
                acc4[t] = __builtin_amdgcn_mfma_f32_16x16x32_f16(a5[s], b, acc4[t], 0, 0, 0);
            }

        // ---- segment max over 8 rows (q0|q1 -> y0, q2|q3 -> y1) & store ----
#pragma unroll
        for (int t = 0; t < 4; ++t) {
            float pm = fmaxf(fmaxf(acc4[t][0], acc4[t][1]),
                             fmaxf(acc4[t][2], acc4[t][3]));
            pm = fmaxf(pm, __shfl_xor(pm, 16, 64));
            if ((q & 1) == 0) {
                const int y = tile * 2 + (q >> 1);
                out[(long)y * 64 + t * 16 + n0] = pm;
            }
        }
    }
}

extern "C" void kernel_launch(void* const* d_in, const int* in_sizes, int n_in,
                              void* d_out, int out_size, void* d_ws, size_t ws_size,
                              hipStream_t stream) {
    (void)in_sizes; (void)n_in; (void)d_ws; (void)ws_size; (void)out_size;
    pointnet_fused<<<512, 512, 0, stream>>>(
        (const float*)d_in[0],   // x
        (const float*)d_in[1],   // pos_x
        (const float*)d_in[2],   // pos_y
        (const int*)  d_in[3],   // x_idx
        (const float*)d_in[5],  (const float*)d_in[6],   // W0a, b0a
        (const float*)d_in[7],  (const float*)d_in[8],   // W1a, b1a
        (const float*)d_in[9],                            // Wsa
        (const float*)d_in[10], (const float*)d_in[11],  // W0b, b0b
        (const float*)d_in[12], (const float*)d_in[13],  // W1b, b1b
        (float*)d_out);
}